// Round 1
// 379.701 us; speedup vs baseline: 1.0455x; 1.0455x over previous
//
#include <hip/hip_runtime.h>
#include <stdint.h>

// SNN pipeline, algebraically fused: y2 = x @ (Wh@Wp)^T + (Wh@bp + bh), then
// T-parallel LIF scan (shadowing warm-up), pool+head.
// r7: main GEMM = asymmetric f16 emulation (A single f16 plane, B f16 hi/lo,
//     2 MFMA products). r8: Y2 intermediate stored f16. r9: gemm_main ported
//     to 256^2 8-wave phase-split schedule (T2+T3+T4+T5): BK=32, 4 phases x
//     16 MFMA per K-step (2 B planes), triple-buffered LDS (144 KB), counted
//     vmcnt(6) (never drain-0 in steady state), LDS XOR bank-swizzle via
//     pre-swizzled global source + swizzled ds_read (rule #21), setprio(1)
//     around MFMA clusters.

typedef short v8s __attribute__((ext_vector_type(8)));
typedef _Float16 v8h __attribute__((ext_vector_type(8)));
typedef float v4f __attribute__((ext_vector_type(4)));

#define GAS __attribute__((address_space(1)))
#define LAS __attribute__((address_space(3)))

__device__ __forceinline__ unsigned short f2bf(float f) {
  unsigned int u = __float_as_uint(f);
  u += 0x7fffu + ((u >> 16) & 1u);   // round-to-nearest-even
  return (unsigned short)(u >> 16);
}
__device__ __forceinline__ float bf2f(unsigned short h) {
  return __uint_as_float(((unsigned int)h) << 16);
}
__device__ __forceinline__ unsigned short f2h(float f) {       // f32->f16 RNE
  union { _Float16 h; unsigned short u; } c;
  c.h = (_Float16)f;
  return c.u;
}
__device__ __forceinline__ float h2f(unsigned short u) {
  union { unsigned short u; _Float16 h; } c;
  c.u = u;
  return (float)c.h;
}

__device__ __forceinline__ void gld_lds16(const void* g, void* l) {
  __builtin_amdgcn_global_load_lds((const GAS void*)g, (LAS void*)l, 16, 0, 0);
}

__device__ __forceinline__ void split4(const float4 x, ushort4* h, ushort4* l) {
  h->x = f2bf(x.x); l->x = f2bf(x.x - bf2f(h->x));
  h->y = f2bf(x.y); l->y = f2bf(x.y - bf2f(h->y));
  h->z = f2bf(x.z); l->z = f2bf(x.z - bf2f(h->z));
  h->w = f2bf(x.w); l->w = f2bf(x.w - bf2f(h->w));
}

// Fused preprocessing (one launch, independent block ranges):
//  [0, 32768):      x -> f16 plane Xh           (192 MB traffic, HBM-bound)
//  [32768, 33792):  transpose+split W_proj -> WpT bf16 hi/lo
//  [33792, 34816):  split W_hid -> Wh bf16 hi/lo
//  [34816, 35072):  bc[g] = Wh[g,:].b_proj + b_hid[g]  (4 waves/block)
__global__ void __launch_bounds__(256) prep_kernel(
    const float* __restrict__ x,
    const float* __restrict__ W_proj, const float* __restrict__ W_hid,
    const float* __restrict__ b_proj, const float* __restrict__ b_hid,
    unsigned short* __restrict__ Xh,
    unsigned short* __restrict__ WpTh, unsigned short* __restrict__ WpTl,
    unsigned short* __restrict__ Whh, unsigned short* __restrict__ Whl,
    float* __restrict__ bc) {
  __shared__ float t[32][33];
  const int blk = blockIdx.x, tid = threadIdx.x;
  if (blk < 32768) {
    const int i = blk * 256 + tid;           // 8388608 float4 = 32M floats
    float4 v = ((const float4*)x)[i];
    ushort4 h;
    h.x = f2h(v.x); h.y = f2h(v.y); h.z = f2h(v.z); h.w = f2h(v.w);
    ((ushort4*)Xh)[i] = h;
  } else if (blk < 33792) {
    const int b2 = blk - 32768;
    const int tx = tid & 31, ty = tid >> 5;  // 32x8
    const int bx = b2 & 31, by = b2 >> 5;
    const int xc = bx * 32 + tx;
    const int yb = by * 32;
#pragma unroll
    for (int j = 0; j < 4; ++j) t[ty + 8 * j][tx] = W_proj[(size_t)(yb + ty + 8 * j) * 1024 + xc];
    __syncthreads();
    const int xo = yb + tx;
#pragma unroll
    for (int j = 0; j < 4; ++j) {
      const float v = t[tx][ty + 8 * j];
      const unsigned short h = f2bf(v);
      const size_t o = (size_t)(bx * 32 + ty + 8 * j) * 1024 + xo;
      WpTh[o] = h;
      WpTl[o] = f2bf(v - bf2f(h));
    }
  } else if (blk < 34816) {
    const int i = (blk - 33792) * 256 + tid; // 262144 float4 = 1M floats
    float4 v = ((const float4*)W_hid)[i];
    ushort4 h, l;
    split4(v, &h, &l);
    ((ushort4*)Whh)[i] = h;
    ((ushort4*)Whl)[i] = l;
  } else {
    const int g = (blk - 34816) * 4 + (tid >> 6);
    const int lane = tid & 63;
    const float* wr = W_hid + (size_t)g * 1024;
    float s = 0.f;
#pragma unroll
    for (int i = 0; i < 16; ++i) s += wr[lane + 64 * i] * b_proj[lane + 64 * i];
#pragma unroll
    for (int off = 32; off > 0; off >>= 1) s += __shfl_down(s, off);
    if (lane == 0) bc[g] = s + b_hid[g];
  }
}

// Weight GEMM: Wc = Wh @ WpT^T, bf16 hi/lo 3-product (near-fp32 exact),
// M=N=K=1024, 128x128 tile. Epilogue stores Wc split to f16 hi/lo (22 bits).
__global__ void __launch_bounds__(256, 2)
gemm_w(const unsigned short* __restrict__ Ah, const unsigned short* __restrict__ Al,
       const unsigned short* __restrict__ Bh, const unsigned short* __restrict__ Bl,
       unsigned short* __restrict__ outH, unsigned short* __restrict__ outL) {
  constexpr int K = 1024, N = 1024;
  __shared__ unsigned short lA[2][128 * 32];
  __shared__ unsigned short lB[2][128 * 32];

  const int tid = threadIdx.x;
  const int mt = blockIdx.x & 7, nt = blockIdx.x >> 3;  // 8x8 grid
  const int m0 = mt * 128, n0 = nt * 128;

  const int lane = tid & 63, wave = tid >> 6;
  const int wm = (wave >> 1) * 64, wn = (wave & 1) * 64;
  const int quad = lane >> 4, r = lane & 15;
  const int srow = tid >> 2, scol = (tid & 3) * 8;

  v4f acc[4][4];
#pragma unroll
  for (int i = 0; i < 4; ++i)
#pragma unroll
    for (int j = 0; j < 4; ++j) acc[i][j] = v4f{0.f, 0.f, 0.f, 0.f};

  const unsigned short* gAh = Ah + (size_t)(m0 + srow) * K + scol;
  const unsigned short* gAl = Al + (size_t)(m0 + srow) * K + scol;
  const unsigned short* gBh = Bh + (size_t)(n0 + srow) * K + scol;
  const unsigned short* gBl = Bl + (size_t)(n0 + srow) * K + scol;

  for (int kt = 0; kt < K; kt += 32) {
    gld_lds16(gAh + kt,          &lA[0][tid * 8]);
    gld_lds16(gAh + kt + 64 * K, &lA[0][tid * 8 + 64 * 32]);
    gld_lds16(gAl + kt,          &lA[1][tid * 8]);
    gld_lds16(gAl + kt + 64 * K, &lA[1][tid * 8 + 64 * 32]);
    gld_lds16(gBh + kt,          &lB[0][tid * 8]);
    gld_lds16(gBh + kt + 64 * K, &lB[0][tid * 8 + 64 * 32]);
    gld_lds16(gBl + kt,          &lB[1][tid * 8]);
    gld_lds16(gBl + kt + 64 * K, &lB[1][tid * 8 + 64 * 32]);
    __syncthreads();

    v8s ah[4], al[4], bh[4], bl[4];
#pragma unroll
    for (int i = 0; i < 4; ++i) {
      ah[i] = *(const v8s*)&lA[0][(wm + i * 16 + r) * 32 + quad * 8];
      al[i] = *(const v8s*)&lA[1][(wm + i * 16 + r) * 32 + quad * 8];
      bh[i] = *(const v8s*)&lB[0][(wn + i * 16 + r) * 32 + quad * 8];
      bl[i] = *(const v8s*)&lB[1][(wn + i * 16 + r) * 32 + quad * 8];
    }
#pragma unroll
    for (int i = 0; i < 4; ++i)
#pragma unroll
      for (int j = 0; j < 4; ++j) {
        acc[i][j] = __builtin_amdgcn_mfma_f32_16x16x32_bf16(ah[i], bh[j], acc[i][j], 0, 0, 0);
        acc[i][j] = __builtin_amdgcn_mfma_f32_16x16x32_bf16(ah[i], bl[j], acc[i][j], 0, 0, 0);
        acc[i][j] = __builtin_amdgcn_mfma_f32_16x16x32_bf16(al[i], bh[j], acc[i][j], 0, 0, 0);
      }
    __syncthreads();
  }

#pragma unroll
  for (int i = 0; i < 4; ++i)
#pragma unroll
    for (int j = 0; j < 4; ++j) {
      const int gn = n0 + wn + j * 16 + r;
#pragma unroll
      for (int q2 = 0; q2 < 4; ++q2) {
        const int gm = m0 + wm + i * 16 + quad * 4 + q2;
        const float y = acc[i][j][q2];
        const unsigned short h = f2h(y);           // f16 hi
        const size_t o = (size_t)gm * N + gn;
        outH[o] = h;
        outL[o] = f2h(y - h2f(h));                 // f16 lo
      }
    }
}

// Main GEMM: Y2(f16) = Xf16 @ Wc^T + bc. 256x256 tile, 8 waves (2Mx4N) each
// owning 128x64. BK=32, both B planes per K-step -> 64 MFMA/wave/K-step split
// into 4 phases x 16 MFMA. Triple-buffered LDS (3 x 48KB), loads issued 2
// K-steps ahead, counted vmcnt(6). Bank-swizzle: logical slot q at physical
// slot q ^ ((row>>1)&3) -> frag reads hit all 8 bank groups (2-way = free).
// global_load_lds writes linearly, so the SOURCE address is pre-swizzled and
// the ds_read applies the same XOR (rule #21).
__global__ void __launch_bounds__(512, 2)
gemm_main(const unsigned short* __restrict__ Ah,
          const unsigned short* __restrict__ Bh, const unsigned short* __restrict__ Bl,
          const float* __restrict__ bias, unsigned short* __restrict__ outH, int M) {
  constexpr int K = 1024, N = 1024;
  __shared__ unsigned short lA[3][8192];   // 48 KB
  __shared__ unsigned short lB0[3][8192];  // 48 KB
  __shared__ unsigned short lB1[3][8192];  // 48 KB

  const int tid = threadIdx.x;
  const int band = (M >> 8) >> 3;            // 16 for M=32768
  const int c = blockIdx.x & 7, idx = blockIdx.x >> 3;   // 512 blocks, %8==0
  const int mt = c * band + (idx >> 2), nt = idx & 3;
  const int m0 = mt * 256, n0 = nt * 256;

  const int lane = tid & 63, wave = tid >> 6;
  const int wm = (wave >> 2) * 128, wn = (wave & 3) * 64;
  const int quad = lane >> 4, r = lane & 15;
  // swizzled read column (shorts): physical slot = quad ^ ((row>>1)&3);
  // row = wm|wn + 16*i + r and wm,wn,16*i contribute 0 mod 4 to row>>1.
  const int cs = (quad ^ ((r >> 1) & 3)) * 8;
  const int aoff = (wm + r) * 32 + cs;   // + i*512 per fragment
  const int boff = (wn + r) * 32 + cs;   // + j*512 per fragment

  // staging: thread t -> tile row t>>2, physical slot t&3 (linear LDS dest);
  // source slot inverse-swizzled so the LDS image is the swizzled layout.
  const int srow = tid >> 2;                           // 0..127 (+128 call 1)
  const int sslot = (tid & 3) ^ ((tid >> 3) & 3);      // same for row+128

  const unsigned short* gA  = Ah + (size_t)(m0 + srow) * K + sslot * 8;
  const unsigned short* gB0p = Bh + (size_t)(n0 + srow) * K + sslot * 8;
  const unsigned short* gB1p = Bl + (size_t)(n0 + srow) * K + sslot * 8;

  v4f acc[8][4];
#pragma unroll
  for (int i = 0; i < 8; ++i)
#pragma unroll
    for (int j = 0; j < 4; ++j) acc[i][j] = v4f{0.f, 0.f, 0.f, 0.f};

  // prologue: stage K-step 0 -> buf0, K-step 1 -> buf1 (6 loads each)
#pragma unroll
  for (int p = 0; p < 2; ++p) {
    const int kt = p * 32;
    gld_lds16(gA  + kt,           &lA[p][tid * 8]);
    gld_lds16(gA  + kt + 128 * K, &lA[p][4096 + tid * 8]);
    gld_lds16(gB0p + kt,           &lB0[p][tid * 8]);
    gld_lds16(gB0p + kt + 128 * K, &lB0[p][4096 + tid * 8]);
    gld_lds16(gB1p + kt,           &lB1[p][tid * 8]);
    gld_lds16(gB1p + kt + 128 * K, &lB1[p][4096 + tid * 8]);
  }
  asm volatile("s_waitcnt vmcnt(6)" ::: "memory");   // buf0 complete
  __builtin_amdgcn_s_barrier();
  __builtin_amdgcn_sched_barrier(0);

  int cur = 0, nxt = 2;
#pragma unroll 1
  for (int t = 0; t < 32; ++t) {
    const unsigned short* la = lA[cur];
    const unsigned short* lb0 = lB0[cur];
    const unsigned short* lb1 = lB1[cur];
    unsigned short* sa = lA[nxt];
    unsigned short* sb0 = lB0[nxt];
    unsigned short* sb1 = lB1[nxt];
    const int kp = (t + 2) * 32;
    const bool pf = (t < 30);

    v8h ah[4], ah2[4], bh[4], bl[4];

    // ---- phase 0: A[0..63] x Bh ----
#pragma unroll
    for (int i = 0; i < 4; ++i) ah[i] = *(const v8h*)&la[aoff + i * 512];
#pragma unroll
    for (int j = 0; j < 4; ++j) bh[j] = *(const v8h*)&lb0[boff + j * 512];
    if (pf) gld_lds16(gA + kp, &sa[tid * 8]);
    __builtin_amdgcn_s_barrier();
    asm volatile("s_waitcnt lgkmcnt(0)" ::: "memory");
    __builtin_amdgcn_sched_barrier(0);
    __builtin_amdgcn_s_setprio(1);
#pragma unroll
    for (int i = 0; i < 4; ++i)
#pragma unroll
      for (int j = 0; j < 4; ++j)
        acc[i][j] = __builtin_amdgcn_mfma_f32_16x16x32_f16(ah[i], bh[j], acc[i][j], 0, 0, 0);
    __builtin_amdgcn_s_setprio(0);
    __builtin_amdgcn_s_barrier();
    __builtin_amdgcn_sched_barrier(0);

    // ---- phase 1: A[0..63] x Bl ----
#pragma unroll
    for (int j = 0; j < 4; ++j) bl[j] = *(const v8h*)&lb1[boff + j * 512];
    if (pf) gld_lds16(gA + kp + 128 * K, &sa[4096 + tid * 8]);
    __builtin_amdgcn_s_barrier();
    asm volatile("s_waitcnt lgkmcnt(0)" ::: "memory");
    __builtin_amdgcn_sched_barrier(0);
    __builtin_amdgcn_s_setprio(1);
#pragma unroll
    for (int i = 0; i < 4; ++i)
#pragma unroll
      for (int j = 0; j < 4; ++j)
        acc[i][j] = __builtin_amdgcn_mfma_f32_16x16x32_f16(ah[i], bl[j], acc[i][j], 0, 0, 0);
    __builtin_amdgcn_s_setprio(0);
    __builtin_amdgcn_s_barrier();
    __builtin_amdgcn_sched_barrier(0);

    // ---- phase 2: A[64..127] x Bh ----
#pragma unroll
    for (int i = 0; i < 4; ++i) ah2[i] = *(const v8h*)&la[aoff + (4 + i) * 512];
    if (pf) {
      gld_lds16(gB0p + kp,           &sb0[tid * 8]);
      gld_lds16(gB0p + kp + 128 * K, &sb0[4096 + tid * 8]);
    }
    __builtin_amdgcn_s_barrier();
    asm volatile("s_waitcnt lgkmcnt(0)" ::: "memory");
    __builtin_amdgcn_sched_barrier(0);
    __builtin_amdgcn_s_setprio(1);
#pragma unroll
    for (int i = 0; i < 4; ++i)
#pragma unroll
      for (int j = 0; j < 4; ++j)
        acc[4 + i][j] = __builtin_amdgcn_mfma_f32_16x16x32_f16(ah2[i], bh[j], acc[4 + i][j], 0, 0, 0);
    __builtin_amdgcn_s_setprio(0);
    __builtin_amdgcn_s_barrier();
    __builtin_amdgcn_sched_barrier(0);

    // ---- phase 3: A[64..127] x Bl (no new ds_reads) ----
    if (pf) {
      gld_lds16(gB1p + kp,           &sb1[tid * 8]);
      gld_lds16(gB1p + kp + 128 * K, &sb1[4096 + tid * 8]);
    }
    __builtin_amdgcn_s_barrier();
    __builtin_amdgcn_s_setprio(1);
#pragma unroll
    for (int i = 0; i < 4; ++i)
#pragma unroll
      for (int j = 0; j < 4; ++j)
        acc[4 + i][j] = __builtin_amdgcn_mfma_f32_16x16x32_f16(ah2[i], bl[j], acc[4 + i][j], 0, 0, 0);
    __builtin_amdgcn_s_setprio(0);
    // counted wait: allow the 6 loads of K-step t+2 to stay in flight;
    // guarantees K-step t+1's buffer complete before any wave reads it.
    if (t < 30) asm volatile("s_waitcnt vmcnt(6)" ::: "memory");
    else        asm volatile("s_waitcnt vmcnt(0)" ::: "memory");
    __builtin_amdgcn_s_barrier();
    __builtin_amdgcn_sched_barrier(0);

    cur = (cur == 2) ? 0 : cur + 1;
    nxt = (nxt == 2) ? 0 : nxt + 1;
  }

  // epilogue: C[m = quad*4+q2][n = lane&15]; store f16 with bias
  float bv[4];
#pragma unroll
  for (int j = 0; j < 4; ++j) bv[j] = bias[n0 + wn + j * 16 + r];
#pragma unroll
  for (int i = 0; i < 8; ++i)
#pragma unroll
    for (int j = 0; j < 4; ++j) {
      const int gn = n0 + wn + j * 16 + r;
#pragma unroll
      for (int q2 = 0; q2 < 4; ++q2) {
        const int gm = m0 + wm + i * 16 + quad * 4 + q2;
        outH[(size_t)gm * N + gn] = f2h(acc[i][j][q2] + bv[j]);
      }
    }
}

// T-parallel LIF over f16 y2: 8 chunks of 128 steps, 32-step shadowing
// warm-up (state contracts x0.5/step; 2^-32 residual ~1e-9 -> no flips).
__global__ void __launch_bounds__(256) lif_part_kernel(const unsigned short* __restrict__ y2,
                                                       float* __restrict__ part) {
  const int idx = blockIdx.x * 256 + threadIdx.x;  // chunk*32768 + ch
  const int ch = idx & 32767, chunk = idx >> 15;
  const unsigned short* p = y2 + ((size_t)(ch >> 10) << 20) + (ch & 1023);
  const int t0 = chunk << 7;
  float v = 0.f;
  if (chunk) {  // uniform per wave (32768 % 64 == 0)
    const unsigned short* pw = p + (size_t)(t0 - 32) * 1024;
    for (int b = 0; b < 32; b += 16) {
      float x[16];
#pragma unroll
      for (int i = 0; i < 16; ++i) x[i] = h2f(pw[(size_t)(b + i) * 1024]);
#pragma unroll
      for (int i = 0; i < 16; ++i) {
        v += (x[i] - v) * 0.5f;
        if (v >= 1.0f) v -= 1.0f;
      }
    }
  }
  float cnt = 0.f;
  const unsigned short* pm = p + (size_t)t0 * 1024;
  for (int b = 0; b < 128; b += 16) {
    float x[16];
#pragma unroll
    for (int i = 0; i < 16; ++i) x[i] = h2f(pm[(size_t)(b + i) * 1024]);
#pragma unroll
    for (int i = 0; i < 16; ++i) {
      v += (x[i] - v) * 0.5f;              // exact reference op order
      float s = (v >= 1.0f) ? 1.0f : 0.0f;
      cnt += s;
      v -= s;
    }
  }
  part[idx] = cnt;
}

// out[b,o] = (sum_c part[c][b,:]).W_out[o,:]/1024 + b_out[o]; one wave each.
// part holds integer spike counts -> cross-chunk sum exact in any order.
__global__ void __launch_bounds__(64) head_kernel(const float* __restrict__ part,
                                                  const float* __restrict__ W_out,
                                                  const float* __restrict__ b_out,
                                                  float* __restrict__ out) {
  int blk = blockIdx.x;          // 0..319
  int b = blk / 10, o = blk % 10;
  int lane = threadIdx.x;
  const float* wr = W_out + o * 1024;
  float s = 0.f;
#pragma unroll
  for (int i = 0; i < 16; ++i) {
    const int ch = b * 1024 + lane + 64 * i;
    float p = 0.f;
#pragma unroll
    for (int c = 0; c < 8; ++c) p += part[c * 32768 + ch];
    s += p * wr[lane + 64 * i];
  }
#pragma unroll
  for (int off = 32; off > 0; off >>= 1) s += __shfl_down(s, off);
  if (lane == 0) out[b * 10 + o] = s * (1.0f / 1024.0f) + b_out[o];
}

extern "C" void kernel_launch(void* const* d_in, const int* in_sizes, int n_in,
                              void* d_out, int out_size, void* d_ws, size_t ws_size,
                              hipStream_t stream) {
  const float* x      = (const float*)d_in[0];
  const float* W_proj = (const float*)d_in[1];
  const float* b_proj = (const float*)d_in[2];
  const float* W_hid  = (const float*)d_in[3];
  const float* b_hid  = (const float*)d_in[4];
  const float* W_out  = (const float*)d_in[5];
  const float* b_out  = (const float*)d_in[6];
  float* out = (float*)d_out;

  const int M = 32768;  // B*T

  // Workspace (~143 MB): Xh f16 [64M] | Y2 f16 [64M] | weights | bc | part
  char* ws = (char*)d_ws;
  unsigned short* Xh   = (unsigned short*)(ws);
  unsigned short* Y2   = (unsigned short*)(ws + 67108864);
  char* base = ws + 134217728;
  unsigned short* WpTh = (unsigned short*)(base);             // bf16
  unsigned short* WpTl = (unsigned short*)(base + 2097152);
  unsigned short* Whh  = (unsigned short*)(base + 4194304);
  unsigned short* Whl  = (unsigned short*)(base + 6291456);
  unsigned short* Wch  = (unsigned short*)(base + 8388608);   // f16
  unsigned short* Wcl  = (unsigned short*)(base + 10485760);
  float*           bc  = (float*)(base + 12582912);
  float*          part = (float*)(base + 12582912 + 65536);

  prep_kernel<<<35072, 256, 0, stream>>>(x, W_proj, W_hid, b_proj, b_hid,
                                         Xh, WpTh, WpTl, Whh, Whl, bc);
  // Wc[g,d] = sum_h Wh[g,h] * WpT[d,h], stored as f16 hi/lo
  gemm_w<<<64, 256, 0, stream>>>(Whh, Whl, WpTh, WpTl, Wch, Wcl);
  gemm_main<<<512, 512, 0, stream>>>(Xh, Wch, Wcl, bc, Y2, M);
  lif_part_kernel<<<1024, 256, 0, stream>>>(Y2, part);
  head_kernel<<<320, 64, 0, stream>>>(part, W_out, b_out, out);
}

// Round 2
// 376.412 us; speedup vs baseline: 1.0546x; 1.0087x over previous
//
#include <hip/hip_runtime.h>
#include <stdint.h>

// SNN pipeline, algebraically fused: y2 = x @ (Wh@Wp)^T + (Wh@bp + bh), then
// T-parallel LIF scan (shadowing warm-up), pool+head.
// r7: main GEMM = asymmetric f16 emulation (A single f16 plane, B f16 hi/lo,
//     2 MFMA products). r8: Y2 intermediate stored f16. r9: gemm_main 256^2
//     8-wave 4-phase schedule, triple-buffered LDS, counted vmcnt, XOR bank
//     swizzle (conflicts -> 0). r10: one-phase-ahead ds_read pipelining with
//     COUNTED lgkmcnt (was lgkmcnt(0) same-phase -> every phase ate the full
//     LDS round-trip serially; now LDS latency hides under the MFMA burst).

typedef short v8s __attribute__((ext_vector_type(8)));
typedef _Float16 v8h __attribute__((ext_vector_type(8)));
typedef float v4f __attribute__((ext_vector_type(4)));

#define GAS __attribute__((address_space(1)))
#define LAS __attribute__((address_space(3)))

__device__ __forceinline__ unsigned short f2bf(float f) {
  unsigned int u = __float_as_uint(f);
  u += 0x7fffu + ((u >> 16) & 1u);   // round-to-nearest-even
  return (unsigned short)(u >> 16);
}
__device__ __forceinline__ float bf2f(unsigned short h) {
  return __uint_as_float(((unsigned int)h) << 16);
}
__device__ __forceinline__ unsigned short f2h(float f) {       // f32->f16 RNE
  union { _Float16 h; unsigned short u; } c;
  c.h = (_Float16)f;
  return c.u;
}
__device__ __forceinline__ float h2f(unsigned short u) {
  union { unsigned short u; _Float16 h; } c;
  c.u = u;
  return (float)c.h;
}

__device__ __forceinline__ void gld_lds16(const void* g, void* l) {
  __builtin_amdgcn_global_load_lds((const GAS void*)g, (LAS void*)l, 16, 0, 0);
}

__device__ __forceinline__ void split4(const float4 x, ushort4* h, ushort4* l) {
  h->x = f2bf(x.x); l->x = f2bf(x.x - bf2f(h->x));
  h->y = f2bf(x.y); l->y = f2bf(x.y - bf2f(h->y));
  h->z = f2bf(x.z); l->z = f2bf(x.z - bf2f(h->z));
  h->w = f2bf(x.w); l->w = f2bf(x.w - bf2f(h->w));
}

// Fused preprocessing (one launch, independent block ranges):
//  [0, 32768):      x -> f16 plane Xh           (192 MB traffic, HBM-bound)
//  [32768, 33792):  transpose+split W_proj -> WpT bf16 hi/lo
//  [33792, 34816):  split W_hid -> Wh bf16 hi/lo
//  [34816, 35072):  bc[g] = Wh[g,:].b_proj + b_hid[g]  (4 waves/block)
__global__ void __launch_bounds__(256) prep_kernel(
    const float* __restrict__ x,
    const float* __restrict__ W_proj, const float* __restrict__ W_hid,
    const float* __restrict__ b_proj, const float* __restrict__ b_hid,
    unsigned short* __restrict__ Xh,
    unsigned short* __restrict__ WpTh, unsigned short* __restrict__ WpTl,
    unsigned short* __restrict__ Whh, unsigned short* __restrict__ Whl,
    float* __restrict__ bc) {
  __shared__ float t[32][33];
  const int blk = blockIdx.x, tid = threadIdx.x;
  if (blk < 32768) {
    const int i = blk * 256 + tid;           // 8388608 float4 = 32M floats
    float4 v = ((const float4*)x)[i];
    ushort4 h;
    h.x = f2h(v.x); h.y = f2h(v.y); h.z = f2h(v.z); h.w = f2h(v.w);
    ((ushort4*)Xh)[i] = h;
  } else if (blk < 33792) {
    const int b2 = blk - 32768;
    const int tx = tid & 31, ty = tid >> 5;  // 32x8
    const int bx = b2 & 31, by = b2 >> 5;
    const int xc = bx * 32 + tx;
    const int yb = by * 32;
#pragma unroll
    for (int j = 0; j < 4; ++j) t[ty + 8 * j][tx] = W_proj[(size_t)(yb + ty + 8 * j) * 1024 + xc];
    __syncthreads();
    const int xo = yb + tx;
#pragma unroll
    for (int j = 0; j < 4; ++j) {
      const float v = t[tx][ty + 8 * j];
      const unsigned short h = f2bf(v);
      const size_t o = (size_t)(bx * 32 + ty + 8 * j) * 1024 + xo;
      WpTh[o] = h;
      WpTl[o] = f2bf(v - bf2f(h));
    }
  } else if (blk < 34816) {
    const int i = (blk - 33792) * 256 + tid; // 262144 float4 = 1M floats
    float4 v = ((const float4*)W_hid)[i];
    ushort4 h, l;
    split4(v, &h, &l);
    ((ushort4*)Whh)[i] = h;
    ((ushort4*)Whl)[i] = l;
  } else {
    const int g = (blk - 34816) * 4 + (tid >> 6);
    const int lane = tid & 63;
    const float* wr = W_hid + (size_t)g * 1024;
    float s = 0.f;
#pragma unroll
    for (int i = 0; i < 16; ++i) s += wr[lane + 64 * i] * b_proj[lane + 64 * i];
#pragma unroll
    for (int off = 32; off > 0; off >>= 1) s += __shfl_down(s, off);
    if (lane == 0) bc[g] = s + b_hid[g];
  }
}

// Weight GEMM: Wc = Wh @ WpT^T, bf16 hi/lo 3-product (near-fp32 exact),
// M=N=K=1024, 128x128 tile. Epilogue stores Wc split to f16 hi/lo (22 bits).
__global__ void __launch_bounds__(256, 2)
gemm_w(const unsigned short* __restrict__ Ah, const unsigned short* __restrict__ Al,
       const unsigned short* __restrict__ Bh, const unsigned short* __restrict__ Bl,
       unsigned short* __restrict__ outH, unsigned short* __restrict__ outL) {
  constexpr int K = 1024, N = 1024;
  __shared__ unsigned short lA[2][128 * 32];
  __shared__ unsigned short lB[2][128 * 32];

  const int tid = threadIdx.x;
  const int mt = blockIdx.x & 7, nt = blockIdx.x >> 3;  // 8x8 grid
  const int m0 = mt * 128, n0 = nt * 128;

  const int lane = tid & 63, wave = tid >> 6;
  const int wm = (wave >> 1) * 64, wn = (wave & 1) * 64;
  const int quad = lane >> 4, r = lane & 15;
  const int srow = tid >> 2, scol = (tid & 3) * 8;

  v4f acc[4][4];
#pragma unroll
  for (int i = 0; i < 4; ++i)
#pragma unroll
    for (int j = 0; j < 4; ++j) acc[i][j] = v4f{0.f, 0.f, 0.f, 0.f};

  const unsigned short* gAh = Ah + (size_t)(m0 + srow) * K + scol;
  const unsigned short* gAl = Al + (size_t)(m0 + srow) * K + scol;
  const unsigned short* gBh = Bh + (size_t)(n0 + srow) * K + scol;
  const unsigned short* gBl = Bl + (size_t)(n0 + srow) * K + scol;

  for (int kt = 0; kt < K; kt += 32) {
    gld_lds16(gAh + kt,          &lA[0][tid * 8]);
    gld_lds16(gAh + kt + 64 * K, &lA[0][tid * 8 + 64 * 32]);
    gld_lds16(gAl + kt,          &lA[1][tid * 8]);
    gld_lds16(gAl + kt + 64 * K, &lA[1][tid * 8 + 64 * 32]);
    gld_lds16(gBh + kt,          &lB[0][tid * 8]);
    gld_lds16(gBh + kt + 64 * K, &lB[0][tid * 8 + 64 * 32]);
    gld_lds16(gBl + kt,          &lB[1][tid * 8]);
    gld_lds16(gBl + kt + 64 * K, &lB[1][tid * 8 + 64 * 32]);
    __syncthreads();

    v8s ah[4], al[4], bh[4], bl[4];
#pragma unroll
    for (int i = 0; i < 4; ++i) {
      ah[i] = *(const v8s*)&lA[0][(wm + i * 16 + r) * 32 + quad * 8];
      al[i] = *(const v8s*)&lA[1][(wm + i * 16 + r) * 32 + quad * 8];
      bh[i] = *(const v8s*)&lB[0][(wn + i * 16 + r) * 32 + quad * 8];
      bl[i] = *(const v8s*)&lB[1][(wn + i * 16 + r) * 32 + quad * 8];
    }
#pragma unroll
    for (int i = 0; i < 4; ++i)
#pragma unroll
      for (int j = 0; j < 4; ++j) {
        acc[i][j] = __builtin_amdgcn_mfma_f32_16x16x32_bf16(ah[i], bh[j], acc[i][j], 0, 0, 0);
        acc[i][j] = __builtin_amdgcn_mfma_f32_16x16x32_bf16(ah[i], bl[j], acc[i][j], 0, 0, 0);
        acc[i][j] = __builtin_amdgcn_mfma_f32_16x16x32_bf16(al[i], bh[j], acc[i][j], 0, 0, 0);
      }
    __syncthreads();
  }

#pragma unroll
  for (int i = 0; i < 4; ++i)
#pragma unroll
    for (int j = 0; j < 4; ++j) {
      const int gn = n0 + wn + j * 16 + r;
#pragma unroll
      for (int q2 = 0; q2 < 4; ++q2) {
        const int gm = m0 + wm + i * 16 + quad * 4 + q2;
        const float y = acc[i][j][q2];
        const unsigned short h = f2h(y);           // f16 hi
        const size_t o = (size_t)gm * N + gn;
        outH[o] = h;
        outL[o] = f2h(y - h2f(h));                 // f16 lo
      }
    }
}

// Main GEMM: Y2(f16) = Xf16 @ Wc^T + bc. 256x256 tile, 8 waves (2Mx4N) each
// owning 128x64. BK=32, both B planes per K-step -> 64 MFMA/wave/K-step split
// into 4 phases x 16 MFMA. Triple-buffered LDS (3 x 48KB). ds_reads issued
// ONE PHASE AHEAD of their MFMA use, with counted lgkmcnt(N) (N = reads just
// issued) so LDS latency hides under MFMA. Counted vmcnt(4) at P1 confirms
// buffer nxt one phase before P2's cross-K-step prefetch reads it. Bank
// swizzle via pre-swizzled global source + swizzled ds_read addr (rule #21).
__global__ void __launch_bounds__(512, 2)
gemm_main(const unsigned short* __restrict__ Ah,
          const unsigned short* __restrict__ Bh, const unsigned short* __restrict__ Bl,
          const float* __restrict__ bias, unsigned short* __restrict__ outH, int M) {
  constexpr int K = 1024, N = 1024;
  __shared__ unsigned short lA[3][8192];   // 48 KB
  __shared__ unsigned short lB0[3][8192];  // 48 KB
  __shared__ unsigned short lB1[3][8192];  // 48 KB

  const int tid = threadIdx.x;
  const int band = (M >> 8) >> 3;            // 16 for M=32768
  const int c = blockIdx.x & 7, idx = blockIdx.x >> 3;   // 512 blocks, %8==0
  const int mt = c * band + (idx >> 2), nt = idx & 3;
  const int m0 = mt * 256, n0 = nt * 256;

  const int lane = tid & 63, wave = tid >> 6;
  const int wm = (wave >> 2) * 128, wn = (wave & 3) * 64;
  const int quad = lane >> 4, r = lane & 15;
  // swizzled read column (shorts): physical slot = quad ^ ((row>>1)&3)
  const int cs = (quad ^ ((r >> 1) & 3)) * 8;
  const int aoff = (wm + r) * 32 + cs;   // + i*512 per fragment
  const int boff = (wn + r) * 32 + cs;   // + j*512 per fragment

  // staging: thread t -> tile row t>>2, linear LDS slot t&3; global source
  // slot inverse-swizzled so the LDS image is the swizzled layout.
  const int srow = tid >> 2;                           // 0..127 (+128 call 1)
  const int sslot = (tid & 3) ^ ((tid >> 3) & 3);      // same for row+128

  const unsigned short* gA   = Ah + (size_t)(m0 + srow) * K + sslot * 8;
  const unsigned short* gB0p = Bh + (size_t)(n0 + srow) * K + sslot * 8;
  const unsigned short* gB1p = Bl + (size_t)(n0 + srow) * K + sslot * 8;

  v4f acc[8][4];
#pragma unroll
  for (int i = 0; i < 8; ++i)
#pragma unroll
    for (int j = 0; j < 4; ++j) acc[i][j] = v4f{0.f, 0.f, 0.f, 0.f};

  // buffer rotation pointers: cur / nxt / nx2 (staging target)
  unsigned short *Ac = lA[0],  *An = lA[1],  *A2 = lA[2];
  unsigned short *Bc = lB0[0], *Bn = lB0[1], *B2 = lB0[2];
  unsigned short *Cc = lB1[0], *Cn = lB1[1], *C2 = lB1[2];

  // prologue: stage K-step 0 -> buf0, K-step 1 -> buf1 (6 loads each)
  gld_lds16(gA,              &Ac[tid * 8]);
  gld_lds16(gA + 128 * K,    &Ac[4096 + tid * 8]);
  gld_lds16(gB0p,            &Bc[tid * 8]);
  gld_lds16(gB0p + 128 * K,  &Bc[4096 + tid * 8]);
  gld_lds16(gB1p,            &Cc[tid * 8]);
  gld_lds16(gB1p + 128 * K,  &Cc[4096 + tid * 8]);
  gld_lds16(gA + 32,             &An[tid * 8]);
  gld_lds16(gA + 32 + 128 * K,   &An[4096 + tid * 8]);
  gld_lds16(gB0p + 32,           &Bn[tid * 8]);
  gld_lds16(gB0p + 32 + 128 * K, &Bn[4096 + tid * 8]);
  gld_lds16(gB1p + 32,           &Cn[tid * 8]);
  gld_lds16(gB1p + 32 + 128 * K, &Cn[4096 + tid * 8]);
  asm volatile("s_waitcnt vmcnt(6)" ::: "memory");   // buf0 complete
  __builtin_amdgcn_s_barrier();
  __builtin_amdgcn_sched_barrier(0);

  // preload P0 operands of K-step 0 from buf0
  v8h ah[4], bh[4];
#pragma unroll
  for (int i = 0; i < 4; ++i) ah[i] = *(const v8h*)&Ac[aoff + i * 512];
#pragma unroll
  for (int j = 0; j < 4; ++j) bh[j] = *(const v8h*)&Bc[boff + j * 512];
  __builtin_amdgcn_sched_barrier(0);

#pragma unroll 1
  for (int t = 0; t < 32; ++t) {
    const int kp = (t + 2) * 32;
    const bool pf = (t < 30);
    v8h bl[4], ah2[4], anx[4], bnx[4];

    // ---- P0: read bl(cur); stage A -> nx2; MFMA ah x bh ----
#pragma unroll
    for (int j = 0; j < 4; ++j) bl[j] = *(const v8h*)&Cc[boff + j * 512];
    if (pf) {
      gld_lds16(gA + kp,           &A2[tid * 8]);
      gld_lds16(gA + kp + 128 * K, &A2[4096 + tid * 8]);
    }
    __builtin_amdgcn_sched_barrier(0);
    __builtin_amdgcn_s_barrier();
    asm volatile("s_waitcnt lgkmcnt(4)" ::: "memory");  // ah,bh ready; bl in flight
    __builtin_amdgcn_sched_barrier(0);
    __builtin_amdgcn_s_setprio(1);
#pragma unroll
    for (int i = 0; i < 4; ++i)
#pragma unroll
      for (int j = 0; j < 4; ++j)
        acc[i][j] = __builtin_amdgcn_mfma_f32_16x16x32_f16(ah[i], bh[j], acc[i][j], 0, 0, 0);
    __builtin_amdgcn_s_setprio(0);
    __builtin_amdgcn_sched_barrier(0);
    __builtin_amdgcn_s_barrier();

    // ---- P1: read ah2(cur); stage B0 -> nx2; MFMA ah x bl ----
#pragma unroll
    for (int i = 0; i < 4; ++i) ah2[i] = *(const v8h*)&Ac[aoff + (4 + i) * 512];
    if (pf) {
      gld_lds16(gB0p + kp,           &B2[tid * 8]);
      gld_lds16(gB0p + kp + 128 * K, &B2[4096 + tid * 8]);
    }
    __builtin_amdgcn_sched_barrier(0);
    __builtin_amdgcn_s_barrier();
    // vmcnt(4): the 4 newest are this iter's A+B0 stages; everything older
    // (buffer nxt's 6 loads) confirmed -> P2 may read buf nxt after barrier.
    asm volatile("s_waitcnt vmcnt(4) lgkmcnt(4)" ::: "memory");  // bl ready
    __builtin_amdgcn_sched_barrier(0);
    __builtin_amdgcn_s_setprio(1);
#pragma unroll
    for (int i = 0; i < 4; ++i)
#pragma unroll
      for (int j = 0; j < 4; ++j)
        acc[i][j] = __builtin_amdgcn_mfma_f32_16x16x32_f16(ah[i], bl[j], acc[i][j], 0, 0, 0);
    __builtin_amdgcn_s_setprio(0);
    __builtin_amdgcn_sched_barrier(0);
    __builtin_amdgcn_s_barrier();

    // ---- P2: read next K-step's ah,bh from buf nxt; stage B1 -> nx2;
    //          MFMA ah2 x bh ----
#pragma unroll
    for (int i = 0; i < 4; ++i) anx[i] = *(const v8h*)&An[aoff + i * 512];
#pragma unroll
    for (int j = 0; j < 4; ++j) bnx[j] = *(const v8h*)&Bn[boff + j * 512];
    if (pf) {
      gld_lds16(gB1p + kp,           &C2[tid * 8]);
      gld_lds16(gB1p + kp + 128 * K, &C2[4096 + tid * 8]);
    }
    __builtin_amdgcn_sched_barrier(0);
    __builtin_amdgcn_s_barrier();
    asm volatile("s_waitcnt lgkmcnt(8)" ::: "memory");  // ah2 ready; anx,bnx in flight
    __builtin_amdgcn_sched_barrier(0);
    __builtin_amdgcn_s_setprio(1);
#pragma unroll
    for (int i = 0; i < 4; ++i)
#pragma unroll
      for (int j = 0; j < 4; ++j)
        acc[4 + i][j] = __builtin_amdgcn_mfma_f32_16x16x32_f16(ah2[i], bh[j], acc[4 + i][j], 0, 0, 0);
    __builtin_amdgcn_s_setprio(0);
    __builtin_amdgcn_sched_barrier(0);
    __builtin_amdgcn_s_barrier();

    // ---- P3: MFMA ah2 x bl (all operands confirmed earlier) ----
    __builtin_amdgcn_s_setprio(1);
#pragma unroll
    for (int i = 0; i < 4; ++i)
#pragma unroll
      for (int j = 0; j < 4; ++j)
        acc[4 + i][j] = __builtin_amdgcn_mfma_f32_16x16x32_f16(ah2[i], bl[j], acc[4 + i][j], 0, 0, 0);
    __builtin_amdgcn_s_setprio(0);
    __builtin_amdgcn_sched_barrier(0);
    __builtin_amdgcn_s_barrier();

    // rotate buffers; promote prefetched operands
    unsigned short* tp;
    tp = Ac; Ac = An; An = A2; A2 = tp;
    tp = Bc; Bc = Bn; Bn = B2; B2 = tp;
    tp = Cc; Cc = Cn; Cn = C2; C2 = tp;
#pragma unroll
    for (int i = 0; i < 4; ++i) { ah[i] = anx[i]; bh[i] = bnx[i]; }
  }

  // epilogue: C[m = quad*4+q2][n = lane&15]; store f16 with bias
  float bv[4];
#pragma unroll
  for (int j = 0; j < 4; ++j) bv[j] = bias[n0 + wn + j * 16 + r];
#pragma unroll
  for (int i = 0; i < 8; ++i)
#pragma unroll
    for (int j = 0; j < 4; ++j) {
      const int gn = n0 + wn + j * 16 + r;
#pragma unroll
      for (int q2 = 0; q2 < 4; ++q2) {
        const int gm = m0 + wm + i * 16 + quad * 4 + q2;
        outH[(size_t)gm * N + gn] = f2h(acc[i][j][q2] + bv[j]);
      }
    }
}

// T-parallel LIF over f16 y2: 8 chunks of 128 steps, 32-step shadowing
// warm-up (state contracts x0.5/step; 2^-32 residual ~1e-9 -> no flips).
__global__ void __launch_bounds__(256) lif_part_kernel(const unsigned short* __restrict__ y2,
                                                       float* __restrict__ part) {
  const int idx = blockIdx.x * 256 + threadIdx.x;  // chunk*32768 + ch
  const int ch = idx & 32767, chunk = idx >> 15;
  const unsigned short* p = y2 + ((size_t)(ch >> 10) << 20) + (ch & 1023);
  const int t0 = chunk << 7;
  float v = 0.f;
  if (chunk) {  // uniform per wave (32768 % 64 == 0)
    const unsigned short* pw = p + (size_t)(t0 - 32) * 1024;
    for (int b = 0; b < 32; b += 16) {
      float x[16];
#pragma unroll
      for (int i = 0; i < 16; ++i) x[i] = h2f(pw[(size_t)(b + i) * 1024]);
#pragma unroll
      for (int i = 0; i < 16; ++i) {
        v += (x[i] - v) * 0.5f;
        if (v >= 1.0f) v -= 1.0f;
      }
    }
  }
  float cnt = 0.f;
  const unsigned short* pm = p + (size_t)t0 * 1024;
  for (int b = 0; b < 128; b += 16) {
    float x[16];
#pragma unroll
    for (int i = 0; i < 16; ++i) x[i] = h2f(pm[(size_t)(b + i) * 1024]);
#pragma unroll
    for (int i = 0; i < 16; ++i) {
      v += (x[i] - v) * 0.5f;              // exact reference op order
      float s = (v >= 1.0f) ? 1.0f : 0.0f;
      cnt += s;
      v -= s;
    }
  }
  part[idx] = cnt;
}

// out[b,o] = (sum_c part[c][b,:]).W_out[o,:]/1024 + b_out[o]; one wave each.
// part holds integer spike counts -> cross-chunk sum exact in any order.
__global__ void __launch_bounds__(64) head_kernel(const float* __restrict__ part,
                                                  const float* __restrict__ W_out,
                                                  const float* __restrict__ b_out,
                                                  float* __restrict__ out) {
  int blk = blockIdx.x;          // 0..319
  int b = blk / 10, o = blk % 10;
  int lane = threadIdx.x;
  const float* wr = W_out + o * 1024;
  float s = 0.f;
#pragma unroll
  for (int i = 0; i < 16; ++i) {
    const int ch = b * 1024 + lane + 64 * i;
    float p = 0.f;
#pragma unroll
    for (int c = 0; c < 8; ++c) p += part[c * 32768 + ch];
    s += p * wr[lane + 64 * i];
  }
#pragma unroll
  for (int off = 32; off > 0; off >>= 1) s += __shfl_down(s, off);
  if (lane == 0) out[b * 10 + o] = s * (1.0f / 1024.0f) + b_out[o];
}

extern "C" void kernel_launch(void* const* d_in, const int* in_sizes, int n_in,
                              void* d_out, int out_size, void* d_ws, size_t ws_size,
                              hipStream_t stream) {
  const float* x      = (const float*)d_in[0];
  const float* W_proj = (const float*)d_in[1];
  const float* b_proj = (const float*)d_in[2];
  const float* W_hid  = (const float*)d_in[3];
  const float* b_hid  = (const float*)d_in[4];
  const float* W_out  = (const float*)d_in[5];
  const float* b_out  = (const float*)d_in[6];
  float* out = (float*)d_out;

  const int M = 32768;  // B*T

  // Workspace (~143 MB): Xh f16 [64M] | Y2 f16 [64M] | weights | bc | part
  char* ws = (char*)d_ws;
  unsigned short* Xh   = (unsigned short*)(ws);
  unsigned short* Y2   = (unsigned short*)(ws + 67108864);
  char* base = ws + 134217728;
  unsigned short* WpTh = (unsigned short*)(base);             // bf16
  unsigned short* WpTl = (unsigned short*)(base + 2097152);
  unsigned short* Whh  = (unsigned short*)(base + 4194304);
  unsigned short* Whl  = (unsigned short*)(base + 6291456);
  unsigned short* Wch  = (unsigned short*)(base + 8388608);   // f16
  unsigned short* Wcl  = (unsigned short*)(base + 10485760);
  float*           bc  = (float*)(base + 12582912);
  float*          part = (float*)(base + 12582912 + 65536);

  prep_kernel<<<35072, 256, 0, stream>>>(x, W_proj, W_hid, b_proj, b_hid,
                                         Xh, WpTh, WpTl, Whh, Whl, bc);
  // Wc[g,d] = sum_h Wh[g,h] * WpT[d,h], stored as f16 hi/lo
  gemm_w<<<64, 256, 0, stream>>>(Whh, Whl, WpTh, WpTl, Wch, Wcl);
  gemm_main<<<512, 512, 0, stream>>>(Xh, Wch, Wcl, bc, Y2, M);
  lif_part_kernel<<<1024, 256, 0, stream>>>(Y2, part);
  head_kernel<<<320, 64, 0, stream>>>(part, W_out, b_out, out);
}